// Round 1
// baseline (145.869 us; speedup 1.0000x reference)
//
#include <hip/hip_runtime.h>

#define Bc 16
#define Hc 512
#define Wc 8192
#define NMAX 64
// H*W = 2^22, W = 2^13

// Kernel 1: per-batch — compute sn/en/valid, write xi_new (as float) to the
// tail of d_out, and build the col->src map in d_ws.
// map[col] >= 0 : gather x[row, map[col]]
// map[col] == -1: write 0
// map[col] == -2: write sep_val
__global__ __launch_bounds__(256) void setup_map_kernel(
    const int* __restrict__ xi,    // (B, NMAX, 2) int32
    const int* __restrict__ Narr,  // (B,) int32
    int* __restrict__ map,         // (B, W) int32  [workspace]
    float* __restrict__ xi_out)    // (B, NMAX, 2) as float32 [tail of d_out]
{
    const int b = blockIdx.x;
    const int tid = threadIdx.x;

    __shared__ int s_s[NMAX];
    __shared__ int s_w[NMAX];
    __shared__ int s_sn[NMAX];
    __shared__ int s_en[NMAX];
    __shared__ int s_valid[NMAX];

    const int Nb = Narr[b];

    if (tid < NMAX) {
        int s = xi[b * NMAX * 2 + tid * 2 + 0];
        int e = xi[b * NMAX * 2 + tid * 2 + 1];
        int valid = (tid < Nb) ? 1 : 0;
        int w = e - s;
        if (w < 0) w = 0;
        if (!valid) w = 0;
        s_s[tid] = s;
        s_w[tid] = w;
        s_valid[tid] = valid;
    }
    __syncthreads();

    if (tid == 0) {
        int c = 0;
        for (int i = 0; i < NMAX; ++i) {
            c += s_w[i];                 // inclusive cumsum
            s_sn[i] = c - s_w[i] + i;
            s_en[i] = c + i;
        }
    }
    __syncthreads();

    if (tid < NMAX) {
        int valid = s_valid[tid];
        xi_out[b * NMAX * 2 + tid * 2 + 0] = valid ? (float)s_sn[tid] : 0.0f;
        xi_out[b * NMAX * 2 + tid * 2 + 1] = valid ? (float)s_en[tid] : 0.0f;
    }

    // Build the column map for this batch.
    for (int col = tid; col < Wc; col += blockDim.x) {
        // searchsorted(en, col, side='right'): first j with en[j] > col
        int lo = 0, hi = NMAX;
        while (lo < hi) {
            int mid = (lo + hi) >> 1;
            if (s_en[mid] > col) hi = mid; else lo = mid + 1;
        }
        int j = (lo < NMAX - 1) ? lo : (NMAX - 1);  // clip to [0, 63]

        int m = -1;  // default: zero
        if (s_valid[j] && col >= s_sn[j] && col < s_en[j]) {
            int src = s_s[j] + (col - s_sn[j]);
            if (src < 0) src = 0;
            if (src > Wc - 1) src = Wc - 1;
            m = src;
        } else if (j >= 1) {
            // separator lives at en[i] for valid i with i < N-1 (en < W is
            // implied by col < W). Only candidate after right-searchsorted
            // is i = j-1 (en[j-1] <= col < en[j]); the clipped j==63 case
            // would need N > 64 which is impossible.
            int i = j - 1;
            if (s_valid[i] && (i < Nb - 1) && s_en[i] == col) m = -2;
        }
        map[b * Wc + col] = m;
    }
}

// Kernel 2: streaming apply. Each thread handles 4 consecutive columns.
__global__ __launch_bounds__(256) void apply_kernel(
    const float* __restrict__ x,
    const int* __restrict__ map,
    const float* __restrict__ sep_param,
    float* __restrict__ out)
{
    const long long flat = ((long long)blockIdx.x * blockDim.x + threadIdx.x) * 4LL;
    const float sep = sep_param[0];

    const int col = (int)(flat & (long long)(Wc - 1));
    const int b = (int)(flat >> 22);  // H*W = 2^22

    const int4 m = *(const int4*)(map + b * Wc + col);
    const float* __restrict__ xrow = x + (flat & ~(long long)(Wc - 1));

    float4 v;
    v.x = (m.x >= 0) ? xrow[m.x] : ((m.x == -2) ? sep : 0.0f);
    v.y = (m.y >= 0) ? xrow[m.y] : ((m.y == -2) ? sep : 0.0f);
    v.z = (m.z >= 0) ? xrow[m.z] : ((m.z == -2) ? sep : 0.0f);
    v.w = (m.w >= 0) ? xrow[m.w] : ((m.w == -2) ? sep : 0.0f);

    *(float4*)(out + flat) = v;
}

extern "C" void kernel_launch(void* const* d_in, const int* in_sizes, int n_in,
                              void* d_out, int out_size, void* d_ws, size_t ws_size,
                              hipStream_t stream) {
    const float* x = (const float*)d_in[0];
    const int* xi = (const int*)d_in[1];
    const int* N = (const int*)d_in[2];
    const float* sep = (const float*)d_in[3];

    float* out_x = (float*)d_out;                              // B*H*W floats
    float* out_xi = out_x + (long long)Bc * Hc * Wc;           // B*NMAX*2 floats
    int* map = (int*)d_ws;                                     // B*W int32 = 512 KB

    setup_map_kernel<<<Bc, 256, 0, stream>>>(xi, N, map, out_xi);

    const long long total = (long long)Bc * Hc * Wc;           // 67108864
    const int blocks = (int)(total / (256 * 4));               // 65536
    apply_kernel<<<blocks, 256, 0, stream>>>(x, map, sep, out_x);
}

// Round 2
// 139.228 us; speedup vs baseline: 1.0477x; 1.0477x over previous
//
#include <hip/hip_runtime.h>

#define Bc 16
#define Hc 512
#define Wc 8192
#define NMAX 64
#define CPB 1024   // columns per block (256 threads x 4)
#define RPB 16     // rows per block

// One fused kernel: per block, rebuild the 64-entry block table (cheap),
// derive the per-thread 4-column map ONCE into registers, then stream
// RPB rows. Common case = contiguous src run -> two aligned float4 loads
// + register alignment select. Zero runs do no loads. Boundary groups
// (~6%) take a scalar fallback.
__global__ __launch_bounds__(256) void fused_compact_kernel(
    const float* __restrict__ x,
    const int* __restrict__ xi,    // (B, NMAX, 2) int32
    const int* __restrict__ Narr,  // (B,) int32
    const float* __restrict__ sep_param,
    float* __restrict__ out_x,     // (B, 1, H, W) float32
    float* __restrict__ out_xi)    // (B, NMAX, 2) as float32
{
    const int tid = threadIdx.x;
    const int colchunk = blockIdx.x;
    const int rowchunk = blockIdx.y;
    const int b = blockIdx.z;

    __shared__ int s_s[NMAX];
    __shared__ int s_sn[NMAX];
    __shared__ int s_en[NMAX];
    __shared__ int s_valid[NMAX];

    const int Nb = Narr[b];

    if (tid < NMAX) {
        int s = xi[b * NMAX * 2 + tid * 2 + 0];
        int e = xi[b * NMAX * 2 + tid * 2 + 1];
        int valid = (tid < Nb) ? 1 : 0;
        int w = e - s;
        if (w < 0) w = 0;
        if (!valid) w = 0;
        s_s[tid] = s;
        s_valid[tid] = valid;
        s_sn[tid] = w;          // temp: width
    }
    __syncthreads();

    if (tid == 0) {
        int c = 0;
        for (int i = 0; i < NMAX; ++i) {
            int w = s_sn[i];
            c += w;                  // inclusive cumsum
            s_sn[i] = c - w + i;
            s_en[i] = c + i;
        }
    }
    __syncthreads();

    // xi_new output (once per batch)
    if (colchunk == 0 && rowchunk == 0 && tid < NMAX) {
        int valid = s_valid[tid];
        out_xi[b * NMAX * 2 + tid * 2 + 0] = valid ? (float)s_sn[tid] : 0.0f;
        out_xi[b * NMAX * 2 + tid * 2 + 1] = valid ? (float)s_en[tid] : 0.0f;
    }

    // ---- per-thread column map (registers, computed once) ----
    const int col0 = colchunk * CPB + tid * 4;

    int m0, m1, m2, m3;
    {
        int mm[4];
        #pragma unroll
        for (int c = 0; c < 4; ++c) {
            const int col = col0 + c;
            // searchsorted(en, col, side='right')
            int lo = 0, hi = NMAX;
            while (lo < hi) {
                int mid = (lo + hi) >> 1;
                if (s_en[mid] > col) hi = mid; else lo = mid + 1;
            }
            int j = (lo < NMAX - 1) ? lo : (NMAX - 1);
            int v = -1;  // zero
            if (s_valid[j] && col >= s_sn[j] && col < s_en[j]) {
                int src = s_s[j] + (col - s_sn[j]);
                if (src < 0) src = 0;
                if (src > Wc - 1) src = Wc - 1;
                v = src;
            } else if (j >= 1) {
                int i = j - 1;
                if (s_valid[i] && (i < Nb - 1) && s_en[i] == col) v = -2;  // sep
            }
            mm[c] = v;
        }
        m0 = mm[0]; m1 = mm[1]; m2 = mm[2]; m3 = mm[3];
    }

    const float sep = sep_param[0];

    const bool contig  = (m0 >= 0) & (m1 == m0 + 1) & (m2 == m0 + 2) & (m3 == m0 + 3);
    const bool allzero = (m0 == -1) & (m1 == -1) & (m2 == -1) & (m3 == -1);
    const int a  = (m0 >= 0) ? (m0 >> 2) : 0;
    const int r  = (m0 >= 0) ? (m0 & 3) : 0;
    // r>0 implies m0+3 <= W-1 so (a+1)*4+3 <= W-1: always in-row. r==0 -> a1=a.
    const int a1 = r ? (a + 1) : a;

    const long long base0 = ((long long)b * Hc + (long long)rowchunk * RPB) * (long long)Wc;

    for (int rr = 0; rr < RPB; ++rr) {
        const long long rowoff = base0 + (long long)rr * Wc;
        const float* __restrict__ xrow = x + rowoff;
        float4 v;
        if (contig) {
            const float4* __restrict__ p = (const float4*)xrow;
            const float4 A = p[a];
            const float4 B = p[a1];
            v.x = (r == 0) ? A.x : (r == 1) ? A.y : (r == 2) ? A.z : A.w;
            v.y = (r == 0) ? A.y : (r == 1) ? A.z : (r == 2) ? A.w : B.x;
            v.z = (r == 0) ? A.z : (r == 1) ? A.w : (r == 2) ? B.x : B.y;
            v.w = (r == 0) ? A.w : (r == 1) ? B.x : (r == 2) ? B.y : B.z;
        } else if (allzero) {
            v = make_float4(0.f, 0.f, 0.f, 0.f);
        } else {
            v.x = (m0 >= 0) ? xrow[m0] : ((m0 == -2) ? sep : 0.f);
            v.y = (m1 >= 0) ? xrow[m1] : ((m1 == -2) ? sep : 0.f);
            v.z = (m2 >= 0) ? xrow[m2] : ((m2 == -2) ? sep : 0.f);
            v.w = (m3 >= 0) ? xrow[m3] : ((m3 == -2) ? sep : 0.f);
        }
        *(float4*)(out_x + rowoff + col0) = v;
    }
}

extern "C" void kernel_launch(void* const* d_in, const int* in_sizes, int n_in,
                              void* d_out, int out_size, void* d_ws, size_t ws_size,
                              hipStream_t stream) {
    const float* x   = (const float*)d_in[0];
    const int*   xi  = (const int*)d_in[1];
    const int*   N   = (const int*)d_in[2];
    const float* sep = (const float*)d_in[3];

    float* out_x  = (float*)d_out;
    float* out_xi = out_x + (long long)Bc * Hc * Wc;

    dim3 grid(Wc / CPB, Hc / RPB, Bc);   // (8, 32, 16) = 4096 blocks
    fused_compact_kernel<<<grid, 256, 0, stream>>>(x, xi, N, sep, out_x, out_xi);
}

// Round 4
// 74.200 us; speedup vs baseline: 1.9659x; 1.8764x over previous
//
#include <hip/hip_runtime.h>

#define Bc 16
#define Hc 512
#define Wc 8192
#define NMAX 64
#define CPB 1024   // columns per block (256 threads x 4)
#define RPB 16     // rows per block

typedef float f32x4 __attribute__((ext_vector_type(4)));

// Fused kernel, wave-uniform zero fast path:
//  - per block: rebuild 64-entry table (cheap), per-thread 4-col map in regs.
//  - ballot over the wave: if NO lane has data (the packed-right zero tail,
//    ~74% of columns), do 16 pure nontemporal float4 stores and exit —
//    fill-shaped, no divergence, no loads.
//  - else: contig-run two-load+select path / scalar fallback at run edges.
__global__ __launch_bounds__(256) void fused_compact_kernel(
    const float* __restrict__ x,
    const int* __restrict__ xi,    // (B, NMAX, 2) int32
    const int* __restrict__ Narr,  // (B,) int32
    const float* __restrict__ sep_param,
    float* __restrict__ out_x,     // (B, 1, H, W) float32
    float* __restrict__ out_xi)    // (B, NMAX, 2) as float32
{
    const int tid = threadIdx.x;
    const int colchunk = blockIdx.x;
    const int rowchunk = blockIdx.y;
    const int b = blockIdx.z;

    __shared__ int s_s[NMAX];
    __shared__ int s_sn[NMAX];
    __shared__ int s_en[NMAX];
    __shared__ int s_valid[NMAX];

    const int Nb = Narr[b];

    if (tid < NMAX) {
        int s = xi[b * NMAX * 2 + tid * 2 + 0];
        int e = xi[b * NMAX * 2 + tid * 2 + 1];
        int valid = (tid < Nb) ? 1 : 0;
        int w = e - s;
        if (w < 0) w = 0;
        if (!valid) w = 0;
        s_s[tid] = s;
        s_valid[tid] = valid;
        s_sn[tid] = w;          // temp: width
    }
    __syncthreads();

    if (tid == 0) {
        int c = 0;
        for (int i = 0; i < NMAX; ++i) {
            int w = s_sn[i];
            c += w;                  // inclusive cumsum
            s_sn[i] = c - w + i;
            s_en[i] = c + i;
        }
    }
    __syncthreads();

    // xi_new output (once per batch)
    if (colchunk == 0 && rowchunk == 0 && tid < NMAX) {
        int valid = s_valid[tid];
        out_xi[b * NMAX * 2 + tid * 2 + 0] = valid ? (float)s_sn[tid] : 0.0f;
        out_xi[b * NMAX * 2 + tid * 2 + 1] = valid ? (float)s_en[tid] : 0.0f;
    }

    // ---- per-thread column map (registers, computed once) ----
    const int col0 = colchunk * CPB + tid * 4;

    int m0, m1, m2, m3;
    {
        int mm[4];
        #pragma unroll
        for (int c = 0; c < 4; ++c) {
            const int col = col0 + c;
            // searchsorted(en, col, side='right')
            int lo = 0, hi = NMAX;
            while (lo < hi) {
                int mid = (lo + hi) >> 1;
                if (s_en[mid] > col) hi = mid; else lo = mid + 1;
            }
            int j = (lo < NMAX - 1) ? lo : (NMAX - 1);
            int v = -1;  // zero
            if (s_valid[j] && col >= s_sn[j] && col < s_en[j]) {
                int src = s_s[j] + (col - s_sn[j]);
                if (src < 0) src = 0;
                if (src > Wc - 1) src = Wc - 1;
                v = src;
            } else if (j >= 1) {
                int i = j - 1;
                if (s_valid[i] && (i < Nb - 1) && s_en[i] == col) v = -2;  // sep
            }
            mm[c] = v;
        }
        m0 = mm[0]; m1 = mm[1]; m2 = mm[2]; m3 = mm[3];
    }

    const long long base0 = ((long long)b * Hc + (long long)rowchunk * RPB) * (long long)Wc;

    // ---- wave-uniform zero fast path (the packed-right tail) ----
    const bool hasdata = (m0 != -1) | (m1 != -1) | (m2 != -1) | (m3 != -1);
    if (__ballot(hasdata) == 0ULL) {
        const f32x4 z = (f32x4){0.f, 0.f, 0.f, 0.f};
        #pragma unroll
        for (int rr = 0; rr < RPB; ++rr) {
            __builtin_nontemporal_store(
                z, (f32x4*)(out_x + base0 + (long long)rr * Wc + col0));
        }
        return;
    }

    // ---- data path ----
    const float sep = sep_param[0];

    const bool contig  = (m0 >= 0) & (m1 == m0 + 1) & (m2 == m0 + 2) & (m3 == m0 + 3);
    const int a  = (m0 >= 0) ? (m0 >> 2) : 0;
    const int r  = (m0 >= 0) ? (m0 & 3) : 0;
    // r>0 implies m0+3 <= W-1 so a1 stays inside the row; r==0 -> a1=a.
    const int a1 = r ? (a + 1) : a;

    #pragma unroll 4
    for (int rr = 0; rr < RPB; ++rr) {
        const long long rowoff = base0 + (long long)rr * Wc;
        const float* __restrict__ xrow = x + rowoff;
        f32x4 v;
        if (contig) {
            const f32x4* __restrict__ p = (const f32x4*)xrow;
            const f32x4 A = p[a];
            const f32x4 B = p[a1];
            v.x = (r == 0) ? A.x : (r == 1) ? A.y : (r == 2) ? A.z : A.w;
            v.y = (r == 0) ? A.y : (r == 1) ? A.z : (r == 2) ? A.w : B.x;
            v.z = (r == 0) ? A.z : (r == 1) ? A.w : (r == 2) ? B.x : B.y;
            v.w = (r == 0) ? A.w : (r == 1) ? B.x : (r == 2) ? B.y : B.z;
        } else {
            v.x = (m0 >= 0) ? xrow[m0] : ((m0 == -2) ? sep : 0.f);
            v.y = (m1 >= 0) ? xrow[m1] : ((m1 == -2) ? sep : 0.f);
            v.z = (m2 >= 0) ? xrow[m2] : ((m2 == -2) ? sep : 0.f);
            v.w = (m3 >= 0) ? xrow[m3] : ((m3 == -2) ? sep : 0.f);
        }
        __builtin_nontemporal_store(v, (f32x4*)(out_x + rowoff + col0));
    }
}

extern "C" void kernel_launch(void* const* d_in, const int* in_sizes, int n_in,
                              void* d_out, int out_size, void* d_ws, size_t ws_size,
                              hipStream_t stream) {
    const float* x   = (const float*)d_in[0];
    const int*   xi  = (const int*)d_in[1];
    const int*   N   = (const int*)d_in[2];
    const float* sep = (const float*)d_in[3];

    float* out_x  = (float*)d_out;
    float* out_xi = out_x + (long long)Bc * Hc * Wc;

    dim3 grid(Wc / CPB, Hc / RPB, Bc);   // (8, 32, 16) = 4096 blocks
    fused_compact_kernel<<<grid, 256, 0, stream>>>(x, xi, N, sep, out_x, out_xi);
}